// Round 9
// baseline (404.256 us; speedup 1.0000x reference)
//
#include <hip/hip_runtime.h>
#include <hip/hip_cooperative_groups.h>
#include <math.h>
#include <float.h>
#include <stdint.h>

namespace cg = cooperative_groups;

#define B_ 4
#define N_ 8192
#define K_ 9
#define NPTS (B_ * N_)           // 32768
#define NROWS (NPTS * K_)        // 294912
#define SPLIT 8
#define CHUNK (N_ / SPLIT)       // 1024
#define NGROUP 32
#define GSIZE (CHUNK / NGROUP)   // 32
#define GSTRIDE 33               // 33 float4 slots/group (512B data + 16B pad)
#define NCOPY 16                 // ACC spreading (atomic de-serialization)

typedef float f4 __attribute__((ext_vector_type(4)));
typedef float f32x2 __attribute__((ext_vector_type(2)));

// ---- packed-pair distance --------------------------------------------------
// EXACTNESS CONTRACT: per element this computes
//   t0 = qx*x; t1 = fma(qy,y,t0); t2 = fma(qz,z,t1); s = qw+w; d = fma(t2,-2,s)
// which mirrors hipcc's default-contraction compilation of the historical
//   dot = q.x*c.x + q.y*c.y + q.z*c.z;  d = (q.w + c.w) - 2.0f*dot;
// v2f32 ops select to v_pk_{mul,add,fma}_f32 on gfx950. Scan, pass1 rescan
// and refill ALL use this function on the same LDS inputs -> bit-identical
// distances -> internally consistent (d,idx) lex order. DO NOT change.
// ROUND-5 LESSON: do NOT cache a whole group's 32 distances in registers
// across extraction phases — scratch spill (hbm 2e7 -> 2e8).
// ROUND-7 LESSON: do NOT fully unroll tail loops — tail 110 -> 149 µs.
__device__ __forceinline__ f32x2 dist2_pk(f32x2 xx, f32x2 yy, f32x2 zz, f32x2 ww,
                                          f32x2 qx, f32x2 qy, f32x2 qz, f32x2 qw) {
  f32x2 t0 = qx * xx;
  f32x2 t1 = __builtin_elementwise_fma(qy, yy, t0);
  f32x2 t2 = __builtin_elementwise_fma(qz, zz, t1);
  f32x2 s  = qw + ww;
  f32x2 m2 = {-2.0f, -2.0f};
  return __builtin_elementwise_fma(t2, m2, s);
}

// ---------------- K1: two-level exact top-9 per 1024-chunk, LDS-staged ----------
// ROUND-7/8 VERIFIED FORM (108.7 µs). SPLIT=8 / 32 groups / 128-thr blocks,
// 2048 blocks = 8/CU (16 waves/CU). Distance-only fminf scan + lazy
// one-window index recovery; refill with full lex exclusion.
#define GDECL(G) float gd##G; int gi##G;
#define SCANG(G)                                                           \
  { float bgd = FLT_MAX; int bq = 0;                                       \
    _Pragma("clang loop unroll(disable)")                                  \
    for (int pr = 0; pr < 16; pr += 4) {                                   \
      const f4* cp = CH + (G * GSTRIDE + 2 * pr);                          \
      f4 A0 = cp[0], B0 = cp[1], A1 = cp[2], B1 = cp[3];                   \
      f4 A2 = cp[4], B2 = cp[5], A3 = cp[6], B3 = cp[7];                   \
      f32x2 dA = dist2_pk(__builtin_shufflevector(A0, A0, 0, 1),           \
                          __builtin_shufflevector(A0, A0, 2, 3),           \
                          __builtin_shufflevector(B0, B0, 0, 1),           \
                          __builtin_shufflevector(B0, B0, 2, 3),           \
                          qx2, qy2, qz2, qw2);                             \
      f32x2 dB = dist2_pk(__builtin_shufflevector(A1, A1, 0, 1),           \
                          __builtin_shufflevector(A1, A1, 2, 3),           \
                          __builtin_shufflevector(B1, B1, 0, 1),           \
                          __builtin_shufflevector(B1, B1, 2, 3),           \
                          qx2, qy2, qz2, qw2);                             \
      f32x2 dC = dist2_pk(__builtin_shufflevector(A2, A2, 0, 1),           \
                          __builtin_shufflevector(A2, A2, 2, 3),           \
                          __builtin_shufflevector(B2, B2, 0, 1),           \
                          __builtin_shufflevector(B2, B2, 2, 3),           \
                          qx2, qy2, qz2, qw2);                             \
      f32x2 dD = dist2_pk(__builtin_shufflevector(A3, A3, 0, 1),           \
                          __builtin_shufflevector(A3, A3, 2, 3),           \
                          __builtin_shufflevector(B3, B3, 0, 1),           \
                          __builtin_shufflevector(B3, B3, 2, 3),           \
                          qx2, qy2, qz2, qw2);                             \
      float d0 = dA.x, d1 = dA.y, d2 = dB.x, d3 = dB.y;                    \
      float d4 = dC.x, d5 = dC.y, d6 = dD.x, d7 = dD.y;                    \
      if (HS) {                                                            \
        int j = G * GSIZE + 2 * pr;                                        \
        d0 = (j + 0 == nl) ? FLT_MAX : d0;                                 \
        d1 = (j + 1 == nl) ? FLT_MAX : d1;                                 \
        d2 = (j + 2 == nl) ? FLT_MAX : d2;                                 \
        d3 = (j + 3 == nl) ? FLT_MAX : d3;                                 \
        d4 = (j + 4 == nl) ? FLT_MAX : d4;                                 \
        d5 = (j + 5 == nl) ? FLT_MAX : d5;                                 \
        d6 = (j + 6 == nl) ? FLT_MAX : d6;                                 \
        d7 = (j + 7 == nl) ? FLT_MAX : d7;                                 \
      }                                                                    \
      float m = fminf(fminf(fminf(d0, d1), fminf(d2, d3)),                 \
                      fminf(fminf(d4, d5), fminf(d6, d7)));                \
      bool lt = m < bgd; bgd = lt ? m : bgd; bq = lt ? pr : bq;            \
    }                                                                      \
    gd##G = bgd; gi##G = -1 - bq; }
#define LMC(G, S)                                                          \
  { bool lt = gd##G < wd##S;                                               \
    wd##S = lt ? gd##G : wd##S; wi##S = lt ? gi##G : wi##S;                \
    wg##S = lt ? G : wg##S; }
#define CMB(S)                                                             \
  { bool lt = wd##S < wda;                                                 \
    wda = lt ? wd##S : wda; wia = lt ? wi##S : wia; wga = lt ? wg##S : wga; }
#define WBK(G)                                                             \
  { bool m = (wg == G); gd##G = m ? nd : gd##G; gi##G = m ? ni : gi##G; }
#define TOURN8()                                                           \
  float e01d, e23d, e45d, e67d, f03d, f47d, md;                            \
  int   e01i, e23i, e45i, e67i, f03i, f47i, mi;                            \
  { bool t;                                                                \
    t = d1 < d0; e01d = t ? d1 : d0; e01i = t ? (j + 1) : (j + 0);         \
    t = d3 < d2; e23d = t ? d3 : d2; e23i = t ? (j + 3) : (j + 2);         \
    t = d5 < d4; e45d = t ? d5 : d4; e45i = t ? (j + 5) : (j + 4);         \
    t = d7 < d6; e67d = t ? d7 : d6; e67i = t ? (j + 7) : (j + 6);         \
    t = e23d < e01d; f03d = t ? e23d : e01d; f03i = t ? e23i : e01i;       \
    t = e67d < e45d; f47d = t ? e67d : e45d; f47i = t ? e67i : e45i;       \
    t = f47d < f03d; md = t ? f47d : f03d; mi = t ? f47i : f03i; }

template <bool HS>
__device__ __forceinline__ void knn_chunk(const f4* CH, f32x2 qx2, f32x2 qy2,
                                          f32x2 qz2, f32x2 qw2,
                                          int nl, int j0, int s, int p,
                                          uint2* __restrict__ PBDI) {
  GDECL(0) GDECL(1) GDECL(2) GDECL(3) GDECL(4) GDECL(5) GDECL(6) GDECL(7)
  GDECL(8) GDECL(9) GDECL(10) GDECL(11) GDECL(12) GDECL(13) GDECL(14) GDECL(15)
  GDECL(16) GDECL(17) GDECL(18) GDECL(19) GDECL(20) GDECL(21) GDECL(22) GDECL(23)
  GDECL(24) GDECL(25) GDECL(26) GDECL(27) GDECL(28) GDECL(29) GDECL(30) GDECL(31)

  SCANG(0) SCANG(1) SCANG(2) SCANG(3) SCANG(4) SCANG(5) SCANG(6) SCANG(7)
  SCANG(8) SCANG(9) SCANG(10) SCANG(11) SCANG(12) SCANG(13) SCANG(14) SCANG(15)
  SCANG(16) SCANG(17) SCANG(18) SCANG(19) SCANG(20) SCANG(21) SCANG(22) SCANG(23)
  SCANG(24) SCANG(25) SCANG(26) SCANG(27) SCANG(28) SCANG(29) SCANG(30) SCANG(31)

#pragma clang loop unroll(disable)
  for (int r = 0; r < K_; ++r) {
    float wda = gd0; int wia = gi0; int wga = 0;
    LMC(1,a) LMC(2,a) LMC(3,a) LMC(4,a) LMC(5,a) LMC(6,a) LMC(7,a)
    float wdb = gd8; int wib = gi8; int wgb = 8;
    LMC(9,b) LMC(10,b) LMC(11,b) LMC(12,b) LMC(13,b) LMC(14,b) LMC(15,b)
    float wdc = gd16; int wic = gi16; int wgc = 16;
    LMC(17,c) LMC(18,c) LMC(19,c) LMC(20,c) LMC(21,c) LMC(22,c) LMC(23,c)
    float wdd = gd24; int wid = gi24; int wgd = 24;
    LMC(25,d) LMC(26,d) LMC(27,d) LMC(28,d) LMC(29,d) LMC(30,d) LMC(31,d)
    CMB(b) CMB(c) CMB(d)
    float wd = wda; int wist = wia; int wg = wga;

    int ab = wg * GSTRIDE;
    int jb = wg * GSIZE;

    // pass1: lazy index recovery over ONE 8-candidate window.
    int wi;
    {
      int bq = (wist >= 0) ? 0 : (-1 - wist);      // window 0/4/8/12
      const f4* cp = CH + (ab + 2 * bq);
      f4 A0 = cp[0], B0 = cp[1], A1 = cp[2], B1 = cp[3];
      f4 A2 = cp[4], B2 = cp[5], A3 = cp[6], B3 = cp[7];
      int j = jb + 2 * bq;
      f32x2 dA = dist2_pk(__builtin_shufflevector(A0, A0, 0, 1),
                          __builtin_shufflevector(A0, A0, 2, 3),
                          __builtin_shufflevector(B0, B0, 0, 1),
                          __builtin_shufflevector(B0, B0, 2, 3),
                          qx2, qy2, qz2, qw2);
      f32x2 dB = dist2_pk(__builtin_shufflevector(A1, A1, 0, 1),
                          __builtin_shufflevector(A1, A1, 2, 3),
                          __builtin_shufflevector(B1, B1, 0, 1),
                          __builtin_shufflevector(B1, B1, 2, 3),
                          qx2, qy2, qz2, qw2);
      f32x2 dC = dist2_pk(__builtin_shufflevector(A2, A2, 0, 1),
                          __builtin_shufflevector(A2, A2, 2, 3),
                          __builtin_shufflevector(B2, B2, 0, 1),
                          __builtin_shufflevector(B2, B2, 2, 3),
                          qx2, qy2, qz2, qw2);
      f32x2 dD = dist2_pk(__builtin_shufflevector(A3, A3, 0, 1),
                          __builtin_shufflevector(A3, A3, 2, 3),
                          __builtin_shufflevector(B3, B3, 0, 1),
                          __builtin_shufflevector(B3, B3, 2, 3),
                          qx2, qy2, qz2, qw2);
      float d0 = dA.x, d1 = dA.y, d2 = dB.x, d3 = dB.y;
      float d4 = dC.x, d5 = dC.y, d6 = dD.x, d7 = dD.y;
      if (HS) {
        d0 = (j + 0 == nl) ? FLT_MAX : d0;
        d1 = (j + 1 == nl) ? FLT_MAX : d1;
        d2 = (j + 2 == nl) ? FLT_MAX : d2;
        d3 = (j + 3 == nl) ? FLT_MAX : d3;
        d4 = (j + 4 == nl) ? FLT_MAX : d4;
        d5 = (j + 5 == nl) ? FLT_MAX : d5;
        d6 = (j + 6 == nl) ? FLT_MAX : d6;
        d7 = (j + 7 == nl) ? FLT_MAX : d7;
      }
      const int IMX = 0x7fffffff;
      int a0 = (d0 == wd) ? (j + 0) : IMX;
      int a1 = (d1 == wd) ? (j + 1) : IMX;
      int a2 = (d2 == wd) ? (j + 2) : IMX;
      int a3 = (d3 == wd) ? (j + 3) : IMX;
      int a4 = (d4 == wd) ? (j + 4) : IMX;
      int a5 = (d5 == wd) ? (j + 5) : IMX;
      int a6 = (d6 == wd) ? (j + 6) : IMX;
      int a7 = (d7 == wd) ? (j + 7) : IMX;
      int m01 = a0 < a1 ? a0 : a1;
      int m23 = a2 < a3 ? a2 : a3;
      int m45 = a4 < a5 ? a4 : a5;
      int m67 = a6 < a7 ? a6 : a7;
      int mA = m01 < m23 ? m01 : m23;
      int mB = m45 < m67 ? m45 : m67;
      int jm = mA < mB ? mA : mB;
      wi = (wist >= 0) ? wist : jm;
    }

    uint2 o; o.x = __float_as_uint(wd); o.y = (unsigned)(j0 + wi);
    PBDI[(size_t)(s * K_ + r) * NPTS + p] = o;     // coalesced 8B

    // refill: lex-min over keys strictly > (wd, wi). FULL lex compare is
    // REQUIRED (excludes the whole extraction history). DO NOT weaken.
    float nd = FLT_MAX; int ni = 0;
#pragma clang loop unroll(disable)
    for (int pr = 0; pr < 16; pr += 4) {
      const f4* cp = CH + (ab + 2 * pr);
      f4 A0 = cp[0], B0 = cp[1], A1 = cp[2], B1 = cp[3];
      f4 A2 = cp[4], B2 = cp[5], A3 = cp[6], B3 = cp[7];
      int j = jb + 2 * pr;
      f32x2 dA = dist2_pk(__builtin_shufflevector(A0, A0, 0, 1),
                          __builtin_shufflevector(A0, A0, 2, 3),
                          __builtin_shufflevector(B0, B0, 0, 1),
                          __builtin_shufflevector(B0, B0, 2, 3),
                          qx2, qy2, qz2, qw2);
      f32x2 dB = dist2_pk(__builtin_shufflevector(A1, A1, 0, 1),
                          __builtin_shufflevector(A1, A1, 2, 3),
                          __builtin_shufflevector(B1, B1, 0, 1),
                          __builtin_shufflevector(B1, B1, 2, 3),
                          qx2, qy2, qz2, qw2);
      f32x2 dC = dist2_pk(__builtin_shufflevector(A2, A2, 0, 1),
                          __builtin_shufflevector(A2, A2, 2, 3),
                          __builtin_shufflevector(B2, B2, 0, 1),
                          __builtin_shufflevector(B2, B2, 2, 3),
                          qx2, qy2, qz2, qw2);
      f32x2 dD = dist2_pk(__builtin_shufflevector(A3, A3, 0, 1),
                          __builtin_shufflevector(A3, A3, 2, 3),
                          __builtin_shufflevector(B3, B3, 0, 1),
                          __builtin_shufflevector(B3, B3, 2, 3),
                          qx2, qy2, qz2, qw2);
      float d0 = dA.x, d1 = dA.y, d2 = dB.x, d3 = dB.y;
      float d4 = dC.x, d5 = dC.y, d6 = dD.x, d7 = dD.y;
      if (HS) {
        d0 = (j + 0 == nl) ? FLT_MAX : d0;
        d1 = (j + 1 == nl) ? FLT_MAX : d1;
        d2 = (j + 2 == nl) ? FLT_MAX : d2;
        d3 = (j + 3 == nl) ? FLT_MAX : d3;
        d4 = (j + 4 == nl) ? FLT_MAX : d4;
        d5 = (j + 5 == nl) ? FLT_MAX : d5;
        d6 = (j + 6 == nl) ? FLT_MAX : d6;
        d7 = (j + 7 == nl) ? FLT_MAX : d7;
      }
      bool k0 = (d0 > wd) | ((d0 == wd) & ((j + 0) > wi));
      bool k1 = (d1 > wd) | ((d1 == wd) & ((j + 1) > wi));
      bool k2 = (d2 > wd) | ((d2 == wd) & ((j + 2) > wi));
      bool k3 = (d3 > wd) | ((d3 == wd) & ((j + 3) > wi));
      bool k4 = (d4 > wd) | ((d4 == wd) & ((j + 4) > wi));
      bool k5 = (d5 > wd) | ((d5 == wd) & ((j + 5) > wi));
      bool k6 = (d6 > wd) | ((d6 == wd) & ((j + 6) > wi));
      bool k7 = (d7 > wd) | ((d7 == wd) & ((j + 7) > wi));
      d0 = k0 ? d0 : FLT_MAX;
      d1 = k1 ? d1 : FLT_MAX;
      d2 = k2 ? d2 : FLT_MAX;
      d3 = k3 ? d3 : FLT_MAX;
      d4 = k4 ? d4 : FLT_MAX;
      d5 = k5 ? d5 : FLT_MAX;
      d6 = k6 ? d6 : FLT_MAX;
      d7 = k7 ? d7 : FLT_MAX;
      TOURN8();
      bool lt = md < nd; nd = lt ? md : nd; ni = lt ? mi : ni;
    }
    WBK(0) WBK(1) WBK(2) WBK(3) WBK(4) WBK(5) WBK(6) WBK(7)
    WBK(8) WBK(9) WBK(10) WBK(11) WBK(12) WBK(13) WBK(14) WBK(15)
    WBK(16) WBK(17) WBK(18) WBK(19) WBK(20) WBK(21) WBK(22) WBK(23)
    WBK(24) WBK(25) WBK(26) WBK(27) WBK(28) WBK(29) WBK(30) WBK(31)
  }
}

__launch_bounds__(128, 4)
__global__ void k_knn(const float* __restrict__ x, uint2* __restrict__ PBDI,
                      double* __restrict__ ACC) {
  __shared__ f4 CH[NGROUP * GSTRIDE];   // 16896 B; 8 blocks/CU = 135 KB
  int bid = blockIdx.x;
  // fold ACC zeroing into the first kernel (saves the memset dispatch);
  // launch boundary orders this before k_fused's atomics. ONLY this change
  // vs the verified R8 k_knn.
  if (bid == 0) {
    for (int t = threadIdx.x; t < NCOPY * 40; t += 128) ACC[t] = 0.0;
  }
  int pg = bid >> 3;                 // 128-point range [0,256)
  int s = bid & (SPLIT - 1);
  int p = pg * 128 + threadIdx.x;
  int b = p >> 13;                   // block-uniform (128-aligned range)
  int n = p & (N_ - 1);
  int bO = b * N_;
  int j0 = s * CHUNK;

  const float* xq = x + 3 * (size_t)p;
  float qa = xq[0], qb = xq[1], qc = xq[2];
  float qw = qa * qa + qb * qb + qc * qc;   // EXACT expression everywhere
  f32x2 qx2 = {qa, qa}, qy2 = {qb, qb}, qz2 = {qc, qc}, qw2 = {qw, qw};

  for (int u = threadIdx.x; u < CHUNK / 2; u += 128) {   // 512 pairs
    const float* xp = x + 3 * (size_t)(bO + j0 + 2 * u);
    float a0 = xp[0], b0 = xp[1], c0 = xp[2];
    float a1 = xp[3], b1 = xp[4], c1 = xp[5];
    int G = u >> 4, rr = u & 15;
    f4 lo = {a0, a1, b0, b1};
    f4 hi = {c0, c1, a0 * a0 + b0 * b0 + c0 * c0, a1 * a1 + b1 * b1 + c1 * c1};
    CH[G * GSTRIDE + 2 * rr] = lo;
    CH[G * GSTRIDE + 2 * rr + 1] = hi;
  }
  __syncthreads();

  int n0 = (pg * 128) & (N_ - 1);    // block-uniform
  int nl = n - j0;                   // local self index (valid only if HS)
  if (s == (n0 >> 10)) knn_chunk<true >(CH, qx2, qy2, qz2, qw2, nl, j0, s, p, PBDI);
  else                 knn_chunk<false>(CH, qx2, qy2, qz2, qw2, nl, j0, s, p, PBDI);
}

// ---------------- K2: FUSED tail (cooperative) ---------------------------------
// k_tail1 + k_mlp2 + k_out in ONE kernel, 512 blocks x 256 threads,
// __launch_bounds__(256,2) -> 2 blocks/CU co-resident (512 total) for
// cg::this_grid().sync(). Stage expressions are BYTE-IDENTICAL to the
// verified R8 kernels; only storage moved:
//   - H1 lives in LDS (23 KB, overlaid on dead LMD/LMI) — kills 23.6 MB
//     of global traffic and k_mlp2's 2-wave/CU load latency.
//   - ext[10] stays in wave-0 registers across the syncs.
//   - ACC reads after grid.sync use agent-scope atomic loads (XCD L2
//     non-coherence, G16).
#define LVL(bdv, biv)                                                     \
  { bool lt = cd < (bdv); float td = (bdv); int ti = (biv);               \
    (bdv) = lt ? cd : (bdv); (biv) = lt ? ci : (biv);                     \
    cd = lt ? td : cd; ci = lt ? ti : ci; }
#define INS9ALL()                                                         \
  LVL(b0d, b0i) LVL(b1d, b1i) LVL(b2d, b2i) LVL(b3d, b3i) LVL(b4d, b4i)  \
  LVL(b5d, b5i) LVL(b6d, b6i) LVL(b7d, b7i) LVL(b8d, b8i)
#define TOP9_DECL()                                                       \
  float b0d = FLT_MAX, b1d = FLT_MAX, b2d = FLT_MAX, b3d = FLT_MAX,       \
        b4d = FLT_MAX, b5d = FLT_MAX, b6d = FLT_MAX, b7d = FLT_MAX,       \
        b8d = FLT_MAX;                                                    \
  int b0i = 0, b1i = 0, b2i = 0, b3i = 0, b4i = 0, b5i = 0, b6i = 0,      \
      b7i = 0, b8i = 0;

#define MKREL(T)                                                          \
  float rx##T, ry##T, rz##T, ph##T;                                       \
  { const float* mp = x + 3 * (size_t)(bO + b##T##i);                     \
    rx##T = mp[0] - qa; ry##T = mp[1] - qb; rz##T = mp[2] - qc;           \
    ph##T = atan2f(ry##T, rx##T); }

#define CE(A, Bv)                                                         \
  { bool lt = ph##Bv < ph##A; float t0;                                   \
    t0 = ph##A; ph##A = lt ? ph##Bv : t0; ph##Bv = lt ? t0 : ph##Bv;      \
    t0 = rx##A; rx##A = lt ? rx##Bv : t0; rx##Bv = lt ? t0 : rx##Bv;      \
    t0 = ry##A; ry##A = lt ? ry##Bv : t0; ry##Bv = lt ? t0 : ry##Bv;      \
    t0 = rz##A; rz##A = lt ? rz##Bv : t0; rz##Bv = lt ? t0 : rz##Bv; }

#define ST9(arr, v0, v1, v2, v3, v4, v5, v6, v7, v8)                      \
  arr[0 * 64 + pl] = v0; arr[1 * 64 + pl] = v1; arr[2 * 64 + pl] = v2;    \
  arr[3 * 64 + pl] = v3; arr[4 * 64 + pl] = v4; arr[5 * 64 + pl] = v5;    \
  arr[6 * 64 + pl] = v6; arr[7 * 64 + pl] = v7; arr[8 * 64 + pl] = v8;

#define ACCLD(i) __hip_atomic_load(&ACC[i], __ATOMIC_RELAXED, __HIP_MEMORY_SCOPE_AGENT)

__launch_bounds__(256, 2)
__global__ void k_fused(const float* __restrict__ x, const uint2* __restrict__ PBDI,
                        const float* __restrict__ W1, const float* __restrict__ b1,
                        const float* __restrict__ g1, const float* __restrict__ be1,
                        const float* __restrict__ W2, const float* __restrict__ b2,
                        const float* __restrict__ g2, const float* __restrict__ be2,
                        double* __restrict__ ACC, float* __restrict__ out) {
  cg::grid_group grid = cg::this_grid();

  // LDS overlay: LMD/LMI (18944 B) are dead after the final merge; H1L
  // (10*576*4 = 23040 B) reuses the same space.
  __shared__ __align__(16) char SMU[23040];
  float* LMD = (float*)SMU;                 // [pl*37 + q*9 + r]
  int*   LMI = (int*)(SMU + 9472);
  float* H1L = (float*)SMU;                 // [c*576 + t*64 + pp]
  __shared__ float  LREL[3][9 * 64];        // [comp][t*64 + pl]
  __shared__ float  LSGN[64];
  __shared__ double sredA[4][20];
  __shared__ float  MR[20];

  int q = threadIdx.x >> 6;              // wave id 0..3
  int pl = threadIdx.x & 63;
  int pbase = blockIdx.x * 64;
  int p = pbase + pl;

  // ======== STAGE A: merge + phi-sort + features + W1 + stats1 (R8 verbatim,
  // H1 -> LDS) ========
  {
    TOP9_DECL();
#pragma clang loop unroll_count(2)
    for (int e = 0; e < 2 * K_; ++e) {
      uint2 v = PBDI[(size_t)(q * 2 * K_ + e) * NPTS + p];
      float cd = __uint_as_float(v.x);
      int ci = (int)v.y;
      INS9ALL();
    }
    int base = pl * 37 + q * 9;
    LMD[base + 0] = b0d; LMD[base + 1] = b1d; LMD[base + 2] = b2d;
    LMD[base + 3] = b3d; LMD[base + 4] = b4d; LMD[base + 5] = b5d;
    LMD[base + 6] = b6d; LMD[base + 7] = b7d; LMD[base + 8] = b8d;
    LMI[base + 0] = b0i; LMI[base + 1] = b1i; LMI[base + 2] = b2i;
    LMI[base + 3] = b3i; LMI[base + 4] = b4i; LMI[base + 5] = b5i;
    LMI[base + 6] = b6i; LMI[base + 7] = b7i; LMI[base + 8] = b8i;
  }
  __syncthreads();

  if (q == 0) {
    int b = p >> 13;
    int bO = b * N_;
    const float* xq = x + 3 * (size_t)p;
    float qa = xq[0], qb = xq[1], qc = xq[2];

    TOP9_DECL();
#pragma clang loop unroll_count(3)
    for (int e = 0; e < 4 * K_; ++e) {   // ascending q (=s) then rank
      float cd = LMD[pl * 37 + e];
      int ci = LMI[pl * 37 + e];
      INS9ALL();
    }

    MKREL(0) MKREL(1) MKREL(2) MKREL(3) MKREL(4)
    MKREL(5) MKREL(6) MKREL(7) MKREL(8)

    CE(0,1)
    CE(1,2) CE(0,1)
    CE(2,3) CE(1,2) CE(0,1)
    CE(3,4) CE(2,3) CE(1,2) CE(0,1)
    CE(4,5) CE(3,4) CE(2,3) CE(1,2) CE(0,1)
    CE(5,6) CE(4,5) CE(3,4) CE(2,3) CE(1,2) CE(0,1)
    CE(6,7) CE(5,6) CE(4,5) CE(3,4) CE(2,3) CE(1,2) CE(0,1)
    CE(7,8) CE(6,7) CE(5,6) CE(4,5) CE(3,4) CE(2,3) CE(1,2) CE(0,1)

    float nx0 = ry0 * rz1 - rz0 * ry1;
    float ny0 = rz0 * rx1 - rx0 * rz1;
    float nz0 = rx0 * ry1 - ry0 * rx1;
    float nrm0 = sqrtf(nx0 * nx0 + ny0 * ny0 + nz0 * nz0) + 1e-6f;
    LSGN[pl] = ((nx0 / nrm0) > 0.0f) ? 1.0f : -1.0f;

    ST9(LREL[0], rx0, rx1, rx2, rx3, rx4, rx5, rx6, rx7, rx8)
    ST9(LREL[1], ry0, ry1, ry2, ry3, ry4, ry5, ry6, ry7, ry8)
    ST9(LREL[2], rz0, rz1, rz2, rz3, rz4, rz5, rz6, rz7, rz8)
  }
  __syncthreads();

  {
    double sum[10], ss[10];
#pragma unroll
    for (int c = 0; c < 10; ++c) { sum[c] = 0.0; ss[c] = 0.0; }

#pragma clang loop unroll(disable)
    for (int rl = threadIdx.x; rl < 9 * 64; rl += 256) {
      int t = rl >> 6;
      int pp = rl & 63;
      int t2 = (t + 1 == K_) ? 0 : t + 1;
      float v1x = LREL[0][t * 64 + pp];
      float v1y = LREL[1][t * 64 + pp];
      float v1z = LREL[2][t * 64 + pp];
      float v2x = LREL[0][t2 * 64 + pp];
      float v2y = LREL[1][t2 * 64 + pp];
      float v2z = LREL[2][t2 * 64 + pp];
      float sgn = LSGN[pp];

      float cx = 0.5f * (v1x + v2x);
      float cy = 0.5f * (v1y + v2y);
      float cz = 0.5f * (v1z + v2z);
      float nx = v1y * v2z - v1z * v2y;
      float ny = v1z * v2x - v1x * v2z;
      float nz = v1x * v2y - v1y * v2x;
      float nrm = sqrtf(nx * nx + ny * ny + nz * nz) + 1e-6f;
      nx /= nrm; ny /= nrm; nz /= nrm;
      nx *= sgn; ny *= sgn; nz *= sgn;
      float pos = (nx * cx + ny * cy + nz * cz) / 1.7320508075688772f;

      float fv[7] = {cx, cy, cz, nx, ny, nz, pos};
#pragma unroll
      for (int c = 0; c < 10; ++c) {
        float h = b1[c];
#pragma unroll
        for (int rr = 0; rr < 7; ++rr) h = fmaf(fv[rr], W1[rr * 10 + c], h);
        H1L[c * 576 + t * 64 + pp] = h;       // LDS, was global H1
        double hd = (double)h;
        sum[c] += hd; ss[c] += hd * hd;
      }
    }

    int lane = threadIdx.x & 63, wv = threadIdx.x >> 6;
#pragma unroll
    for (int c = 0; c < 10; ++c) {
      double a = sum[c];
#pragma unroll
      for (int off = 32; off > 0; off >>= 1) a += __shfl_down(a, off);
      if (lane == 0) sredA[wv][c] = a;
      double qq = ss[c];
#pragma unroll
      for (int off = 32; off > 0; off >>= 1) qq += __shfl_down(qq, off);
      if (lane == 0) sredA[wv][10 + c] = qq;
    }
  }
  __syncthreads();
  if (threadIdx.x < 20) {
    atomicAdd(&ACC[(blockIdx.x & (NCOPY - 1)) * 40 + threadIdx.x],
              sredA[0][threadIdx.x] + sredA[1][threadIdx.x] +
              sredA[2][threadIdx.x] + sredA[3][threadIdx.x]);
  }

  __threadfence();
  grid.sync();                               // stats1 complete

  // ======== STAGE B: bn1 + relu + @W2+b2 per-point; stats2 + ext in regs ====
  if (threadIdx.x < 20) {
    int c = threadIdx.x % 10;
    int half = threadIdx.x / 10;
    double s0 = 0.0, s1 = 0.0;
#pragma unroll
    for (int cc = 0; cc < NCOPY; ++cc) {
      s0 += ACCLD(cc * 40 + c);
      s1 += ACCLD(cc * 40 + 10 + c);
    }
    double mu = s0 / (double)NROWS;
    double var = s1 / (double)NROWS - mu * mu;
    MR[threadIdx.x] = half ? (float)(1.0 / sqrt(var + 1e-5)) : (float)mu;
  }
  __syncthreads();

  float ext[10], sg[10];
  if (q == 0) {
    double sum[10], ss[10];
#pragma unroll
    for (int c = 0; c < 10; ++c) {
      sum[c] = 0.0; ss[c] = 0.0;
      sg[c] = g2[c];
      ext[c] = (sg[c] >= 0.0f) ? -FLT_MAX : FLT_MAX;
    }

#pragma clang loop unroll(disable)
    for (int t = 0; t < K_; ++t) {
      float v[10];
#pragma unroll
      for (int c = 0; c < 10; ++c) {
        float h = H1L[c * 576 + t * 64 + pl];    // LDS, was global H1
        float z = g1[c] * (h - MR[c]) * MR[10 + c] + be1[c];
        v[c] = z > 0.0f ? z : 0.0f;
      }
#pragma unroll
      for (int c = 0; c < 10; ++c) {
        float h = b2[c];
#pragma unroll
        for (int u = 0; u < 10; ++u) h = fmaf(v[u], W2[u * 10 + c], h);
        sum[c] += (double)h;
        ss[c] += (double)h * (double)h;
        ext[c] = (sg[c] >= 0.0f) ? fmaxf(ext[c], h) : fminf(ext[c], h);
      }
    }

#pragma unroll
    for (int c = 0; c < 10; ++c) {
      double a = sum[c];
#pragma unroll
      for (int off = 32; off > 0; off >>= 1) a += __shfl_down(a, off);
      if (pl == 0) sredA[0][c] = a;
      double qq = ss[c];
#pragma unroll
      for (int off = 32; off > 0; off >>= 1) qq += __shfl_down(qq, off);
      if (pl == 0) sredA[0][10 + c] = qq;
    }
  }
  __syncthreads();
  if (threadIdx.x < 20) {
    atomicAdd(&ACC[(blockIdx.x & (NCOPY - 1)) * 40 + 20 + threadIdx.x],
              sredA[0][threadIdx.x]);
  }

  __threadfence();
  grid.sync();                               // stats2 complete

  // ======== STAGE C: bn2 + relu on ext (registers) -> out ====
  if (threadIdx.x < 20) {
    int c = threadIdx.x % 10;
    int half = threadIdx.x / 10;
    double s0 = 0.0, s1 = 0.0;
#pragma unroll
    for (int cc = 0; cc < NCOPY; ++cc) {
      s0 += ACCLD(cc * 40 + 20 + c);
      s1 += ACCLD(cc * 40 + 30 + c);
    }
    double mu = s0 / (double)NROWS;
    double var = s1 / (double)NROWS - mu * mu;
    MR[threadIdx.x] = half ? (float)(1.0 / sqrt(var + 1e-5)) : (float)mu;
  }
  __syncthreads();

  if (q == 0) {
#pragma unroll
    for (int c = 0; c < 10; ++c) {
      float z = g2[c] * (ext[c] - MR[c]) * MR[10 + c] + be2[c];
      z = z > 0.0f ? z : 0.0f;
      out[(size_t)p * 10 + c] = z;
    }
  }
}

extern "C" void kernel_launch(void* const* d_in, const int* in_sizes, int n_in,
                              void* d_out, int out_size, void* d_ws, size_t ws_size,
                              hipStream_t stream) {
  (void)in_sizes; (void)n_in; (void)out_size; (void)ws_size;
  const float* x  = (const float*)d_in[0];
  const float* W1 = (const float*)d_in[1];
  const float* b1 = (const float*)d_in[2];
  const float* g1 = (const float*)d_in[3];
  const float* be1= (const float*)d_in[4];
  const float* W2 = (const float*)d_in[5];
  const float* b2 = (const float*)d_in[6];
  const float* g2 = (const float*)d_in[7];
  const float* be2= (const float*)d_in[8];
  float* out = (float*)d_out;

  char* base = (char*)d_ws;
  uint2*  PBDI = (uint2*)base;                          // 72 slices, 18.9 MB
  double* ACC = (double*)(base + (size_t)SPLIT * K_ * NPTS * 8);  // NCOPY*40

  k_knn<<<(NPTS / 128) * SPLIT, 128, 0, stream>>>(x, PBDI, ACC);

  void* kargs[] = {(void*)&x, (void*)&PBDI, (void*)&W1, (void*)&b1,
                   (void*)&g1, (void*)&be1, (void*)&W2, (void*)&b2,
                   (void*)&g2, (void*)&be2, (void*)&ACC, (void*)&out};
  hipLaunchCooperativeKernel((const void*)k_fused, dim3(NPTS / 64), dim3(256),
                             kargs, 0, stream);
}

// Round 10
// 214.609 us; speedup vs baseline: 1.8837x; 1.8837x over previous
//
#include <hip/hip_runtime.h>
#include <math.h>
#include <float.h>
#include <stdint.h>

#define B_ 4
#define N_ 8192
#define K_ 9
#define NPTS (B_ * N_)           // 32768
#define NROWS (NPTS * K_)        // 294912
#define SPLIT 8
#define CHUNK (N_ / SPLIT)       // 1024
#define NGROUP 32
#define GSIZE (CHUNK / NGROUP)   // 32
#define GSTRIDE 33               // 33 float4 slots/group (512B data + 16B pad)
#define NCOPY 16                 // ACC spreading (atomic de-serialization)

typedef float f4 __attribute__((ext_vector_type(4)));
typedef float f32x2 __attribute__((ext_vector_type(2)));

// ---- packed-pair distance --------------------------------------------------
// EXACTNESS CONTRACT: per element this computes
//   t0 = qx*x; t1 = fma(qy,y,t0); t2 = fma(qz,z,t1); s = qw+w; d = fma(t2,-2,s)
// which mirrors hipcc's default-contraction compilation of the historical
//   dot = q.x*c.x + q.y*c.y + q.z*c.z;  d = (q.w + c.w) - 2.0f*dot;
// v2f32 ops select to v_pk_{mul,add,fma}_f32 on gfx950. Scan, pass1 rescan
// and refill ALL use this function on the same LDS inputs -> bit-identical
// distances -> internally consistent (d,idx) lex order. DO NOT change.
// ROUND-5 LESSON: do NOT cache a whole group's 32 distances in registers
// across extraction phases — scratch spill (hbm 2e7 -> 2e8).
// ROUND-7 LESSON: do NOT fully unroll tail loops — tail 110 -> 149 µs.
// ROUND-9 LESSON: grid-wide sync (cooperative grid.sync OR spin barriers)
// costs ~100 µs per sync on MI355X at 512 blocks — launch boundaries are
// the ONLY cheap global sync. DO NOT fuse stages that need global stats.
__device__ __forceinline__ f32x2 dist2_pk(f32x2 xx, f32x2 yy, f32x2 zz, f32x2 ww,
                                          f32x2 qx, f32x2 qy, f32x2 qz, f32x2 qw) {
  f32x2 t0 = qx * xx;
  f32x2 t1 = __builtin_elementwise_fma(qy, yy, t0);
  f32x2 t2 = __builtin_elementwise_fma(qz, zz, t1);
  f32x2 s  = qw + ww;
  f32x2 m2 = {-2.0f, -2.0f};
  return __builtin_elementwise_fma(t2, m2, s);
}

// ---------------- K1: two-level exact top-9 per 1024-chunk, LDS-staged ----------
// ROUND-7/8 VERIFIED FORM (108.7 µs). SPLIT=8 / 32 groups / 128-thr blocks,
// 2048 blocks = 8/CU (16 waves/CU). Distance-only fminf scan + lazy
// one-window index recovery; refill with full lex exclusion.
#define GDECL(G) float gd##G; int gi##G;
#define SCANG(G)                                                           \
  { float bgd = FLT_MAX; int bq = 0;                                       \
    _Pragma("clang loop unroll(disable)")                                  \
    for (int pr = 0; pr < 16; pr += 4) {                                   \
      const f4* cp = CH + (G * GSTRIDE + 2 * pr);                          \
      f4 A0 = cp[0], B0 = cp[1], A1 = cp[2], B1 = cp[3];                   \
      f4 A2 = cp[4], B2 = cp[5], A3 = cp[6], B3 = cp[7];                   \
      f32x2 dA = dist2_pk(__builtin_shufflevector(A0, A0, 0, 1),           \
                          __builtin_shufflevector(A0, A0, 2, 3),           \
                          __builtin_shufflevector(B0, B0, 0, 1),           \
                          __builtin_shufflevector(B0, B0, 2, 3),           \
                          qx2, qy2, qz2, qw2);                             \
      f32x2 dB = dist2_pk(__builtin_shufflevector(A1, A1, 0, 1),           \
                          __builtin_shufflevector(A1, A1, 2, 3),           \
                          __builtin_shufflevector(B1, B1, 0, 1),           \
                          __builtin_shufflevector(B1, B1, 2, 3),           \
                          qx2, qy2, qz2, qw2);                             \
      f32x2 dC = dist2_pk(__builtin_shufflevector(A2, A2, 0, 1),           \
                          __builtin_shufflevector(A2, A2, 2, 3),           \
                          __builtin_shufflevector(B2, B2, 0, 1),           \
                          __builtin_shufflevector(B2, B2, 2, 3),           \
                          qx2, qy2, qz2, qw2);                             \
      f32x2 dD = dist2_pk(__builtin_shufflevector(A3, A3, 0, 1),           \
                          __builtin_shufflevector(A3, A3, 2, 3),           \
                          __builtin_shufflevector(B3, B3, 0, 1),           \
                          __builtin_shufflevector(B3, B3, 2, 3),           \
                          qx2, qy2, qz2, qw2);                             \
      float d0 = dA.x, d1 = dA.y, d2 = dB.x, d3 = dB.y;                    \
      float d4 = dC.x, d5 = dC.y, d6 = dD.x, d7 = dD.y;                    \
      if (HS) {                                                            \
        int j = G * GSIZE + 2 * pr;                                        \
        d0 = (j + 0 == nl) ? FLT_MAX : d0;                                 \
        d1 = (j + 1 == nl) ? FLT_MAX : d1;                                 \
        d2 = (j + 2 == nl) ? FLT_MAX : d2;                                 \
        d3 = (j + 3 == nl) ? FLT_MAX : d3;                                 \
        d4 = (j + 4 == nl) ? FLT_MAX : d4;                                 \
        d5 = (j + 5 == nl) ? FLT_MAX : d5;                                 \
        d6 = (j + 6 == nl) ? FLT_MAX : d6;                                 \
        d7 = (j + 7 == nl) ? FLT_MAX : d7;                                 \
      }                                                                    \
      float m = fminf(fminf(fminf(d0, d1), fminf(d2, d3)),                 \
                      fminf(fminf(d4, d5), fminf(d6, d7)));                \
      bool lt = m < bgd; bgd = lt ? m : bgd; bq = lt ? pr : bq;            \
    }                                                                      \
    gd##G = bgd; gi##G = -1 - bq; }
#define LMC(G, S)                                                          \
  { bool lt = gd##G < wd##S;                                               \
    wd##S = lt ? gd##G : wd##S; wi##S = lt ? gi##G : wi##S;                \
    wg##S = lt ? G : wg##S; }
#define CMB(S)                                                             \
  { bool lt = wd##S < wda;                                                 \
    wda = lt ? wd##S : wda; wia = lt ? wi##S : wia; wga = lt ? wg##S : wga; }
#define WBK(G)                                                             \
  { bool m = (wg == G); gd##G = m ? nd : gd##G; gi##G = m ? ni : gi##G; }
#define TOURN8()                                                           \
  float e01d, e23d, e45d, e67d, f03d, f47d, md;                            \
  int   e01i, e23i, e45i, e67i, f03i, f47i, mi;                            \
  { bool t;                                                                \
    t = d1 < d0; e01d = t ? d1 : d0; e01i = t ? (j + 1) : (j + 0);         \
    t = d3 < d2; e23d = t ? d3 : d2; e23i = t ? (j + 3) : (j + 2);         \
    t = d5 < d4; e45d = t ? d5 : d4; e45i = t ? (j + 5) : (j + 4);         \
    t = d7 < d6; e67d = t ? d7 : d6; e67i = t ? (j + 7) : (j + 6);         \
    t = e23d < e01d; f03d = t ? e23d : e01d; f03i = t ? e23i : e01i;       \
    t = e67d < e45d; f47d = t ? e67d : e45d; f47i = t ? e67i : e45i;       \
    t = f47d < f03d; md = t ? f47d : f03d; mi = t ? f47i : f03i; }

template <bool HS>
__device__ __forceinline__ void knn_chunk(const f4* CH, f32x2 qx2, f32x2 qy2,
                                          f32x2 qz2, f32x2 qw2,
                                          int nl, int j0, int s, int p,
                                          uint2* __restrict__ PBDI) {
  GDECL(0) GDECL(1) GDECL(2) GDECL(3) GDECL(4) GDECL(5) GDECL(6) GDECL(7)
  GDECL(8) GDECL(9) GDECL(10) GDECL(11) GDECL(12) GDECL(13) GDECL(14) GDECL(15)
  GDECL(16) GDECL(17) GDECL(18) GDECL(19) GDECL(20) GDECL(21) GDECL(22) GDECL(23)
  GDECL(24) GDECL(25) GDECL(26) GDECL(27) GDECL(28) GDECL(29) GDECL(30) GDECL(31)

  SCANG(0) SCANG(1) SCANG(2) SCANG(3) SCANG(4) SCANG(5) SCANG(6) SCANG(7)
  SCANG(8) SCANG(9) SCANG(10) SCANG(11) SCANG(12) SCANG(13) SCANG(14) SCANG(15)
  SCANG(16) SCANG(17) SCANG(18) SCANG(19) SCANG(20) SCANG(21) SCANG(22) SCANG(23)
  SCANG(24) SCANG(25) SCANG(26) SCANG(27) SCANG(28) SCANG(29) SCANG(30) SCANG(31)

#pragma clang loop unroll(disable)
  for (int r = 0; r < K_; ++r) {
    float wda = gd0; int wia = gi0; int wga = 0;
    LMC(1,a) LMC(2,a) LMC(3,a) LMC(4,a) LMC(5,a) LMC(6,a) LMC(7,a)
    float wdb = gd8; int wib = gi8; int wgb = 8;
    LMC(9,b) LMC(10,b) LMC(11,b) LMC(12,b) LMC(13,b) LMC(14,b) LMC(15,b)
    float wdc = gd16; int wic = gi16; int wgc = 16;
    LMC(17,c) LMC(18,c) LMC(19,c) LMC(20,c) LMC(21,c) LMC(22,c) LMC(23,c)
    float wdd = gd24; int wid = gi24; int wgd = 24;
    LMC(25,d) LMC(26,d) LMC(27,d) LMC(28,d) LMC(29,d) LMC(30,d) LMC(31,d)
    CMB(b) CMB(c) CMB(d)
    float wd = wda; int wist = wia; int wg = wga;

    int ab = wg * GSTRIDE;
    int jb = wg * GSIZE;

    // pass1: lazy index recovery over ONE 8-candidate window.
    int wi;
    {
      int bq = (wist >= 0) ? 0 : (-1 - wist);      // window 0/4/8/12
      const f4* cp = CH + (ab + 2 * bq);
      f4 A0 = cp[0], B0 = cp[1], A1 = cp[2], B1 = cp[3];
      f4 A2 = cp[4], B2 = cp[5], A3 = cp[6], B3 = cp[7];
      int j = jb + 2 * bq;
      f32x2 dA = dist2_pk(__builtin_shufflevector(A0, A0, 0, 1),
                          __builtin_shufflevector(A0, A0, 2, 3),
                          __builtin_shufflevector(B0, B0, 0, 1),
                          __builtin_shufflevector(B0, B0, 2, 3),
                          qx2, qy2, qz2, qw2);
      f32x2 dB = dist2_pk(__builtin_shufflevector(A1, A1, 0, 1),
                          __builtin_shufflevector(A1, A1, 2, 3),
                          __builtin_shufflevector(B1, B1, 0, 1),
                          __builtin_shufflevector(B1, B1, 2, 3),
                          qx2, qy2, qz2, qw2);
      f32x2 dC = dist2_pk(__builtin_shufflevector(A2, A2, 0, 1),
                          __builtin_shufflevector(A2, A2, 2, 3),
                          __builtin_shufflevector(B2, B2, 0, 1),
                          __builtin_shufflevector(B2, B2, 2, 3),
                          qx2, qy2, qz2, qw2);
      f32x2 dD = dist2_pk(__builtin_shufflevector(A3, A3, 0, 1),
                          __builtin_shufflevector(A3, A3, 2, 3),
                          __builtin_shufflevector(B3, B3, 0, 1),
                          __builtin_shufflevector(B3, B3, 2, 3),
                          qx2, qy2, qz2, qw2);
      float d0 = dA.x, d1 = dA.y, d2 = dB.x, d3 = dB.y;
      float d4 = dC.x, d5 = dC.y, d6 = dD.x, d7 = dD.y;
      if (HS) {
        d0 = (j + 0 == nl) ? FLT_MAX : d0;
        d1 = (j + 1 == nl) ? FLT_MAX : d1;
        d2 = (j + 2 == nl) ? FLT_MAX : d2;
        d3 = (j + 3 == nl) ? FLT_MAX : d3;
        d4 = (j + 4 == nl) ? FLT_MAX : d4;
        d5 = (j + 5 == nl) ? FLT_MAX : d5;
        d6 = (j + 6 == nl) ? FLT_MAX : d6;
        d7 = (j + 7 == nl) ? FLT_MAX : d7;
      }
      const int IMX = 0x7fffffff;
      int a0 = (d0 == wd) ? (j + 0) : IMX;
      int a1 = (d1 == wd) ? (j + 1) : IMX;
      int a2 = (d2 == wd) ? (j + 2) : IMX;
      int a3 = (d3 == wd) ? (j + 3) : IMX;
      int a4 = (d4 == wd) ? (j + 4) : IMX;
      int a5 = (d5 == wd) ? (j + 5) : IMX;
      int a6 = (d6 == wd) ? (j + 6) : IMX;
      int a7 = (d7 == wd) ? (j + 7) : IMX;
      int m01 = a0 < a1 ? a0 : a1;
      int m23 = a2 < a3 ? a2 : a3;
      int m45 = a4 < a5 ? a4 : a5;
      int m67 = a6 < a7 ? a6 : a7;
      int mA = m01 < m23 ? m01 : m23;
      int mB = m45 < m67 ? m45 : m67;
      int jm = mA < mB ? mA : mB;
      wi = (wist >= 0) ? wist : jm;
    }

    uint2 o; o.x = __float_as_uint(wd); o.y = (unsigned)(j0 + wi);
    PBDI[(size_t)(s * K_ + r) * NPTS + p] = o;     // coalesced 8B

    // refill: lex-min over keys strictly > (wd, wi). FULL lex compare is
    // REQUIRED (excludes the whole extraction history). DO NOT weaken.
    float nd = FLT_MAX; int ni = 0;
#pragma clang loop unroll(disable)
    for (int pr = 0; pr < 16; pr += 4) {
      const f4* cp = CH + (ab + 2 * pr);
      f4 A0 = cp[0], B0 = cp[1], A1 = cp[2], B1 = cp[3];
      f4 A2 = cp[4], B2 = cp[5], A3 = cp[6], B3 = cp[7];
      int j = jb + 2 * pr;
      f32x2 dA = dist2_pk(__builtin_shufflevector(A0, A0, 0, 1),
                          __builtin_shufflevector(A0, A0, 2, 3),
                          __builtin_shufflevector(B0, B0, 0, 1),
                          __builtin_shufflevector(B0, B0, 2, 3),
                          qx2, qy2, qz2, qw2);
      f32x2 dB = dist2_pk(__builtin_shufflevector(A1, A1, 0, 1),
                          __builtin_shufflevector(A1, A1, 2, 3),
                          __builtin_shufflevector(B1, B1, 0, 1),
                          __builtin_shufflevector(B1, B1, 2, 3),
                          qx2, qy2, qz2, qw2);
      f32x2 dC = dist2_pk(__builtin_shufflevector(A2, A2, 0, 1),
                          __builtin_shufflevector(A2, A2, 2, 3),
                          __builtin_shufflevector(B2, B2, 0, 1),
                          __builtin_shufflevector(B2, B2, 2, 3),
                          qx2, qy2, qz2, qw2);
      f32x2 dD = dist2_pk(__builtin_shufflevector(A3, A3, 0, 1),
                          __builtin_shufflevector(A3, A3, 2, 3),
                          __builtin_shufflevector(B3, B3, 0, 1),
                          __builtin_shufflevector(B3, B3, 2, 3),
                          qx2, qy2, qz2, qw2);
      float d0 = dA.x, d1 = dA.y, d2 = dB.x, d3 = dB.y;
      float d4 = dC.x, d5 = dC.y, d6 = dD.x, d7 = dD.y;
      if (HS) {
        d0 = (j + 0 == nl) ? FLT_MAX : d0;
        d1 = (j + 1 == nl) ? FLT_MAX : d1;
        d2 = (j + 2 == nl) ? FLT_MAX : d2;
        d3 = (j + 3 == nl) ? FLT_MAX : d3;
        d4 = (j + 4 == nl) ? FLT_MAX : d4;
        d5 = (j + 5 == nl) ? FLT_MAX : d5;
        d6 = (j + 6 == nl) ? FLT_MAX : d6;
        d7 = (j + 7 == nl) ? FLT_MAX : d7;
      }
      bool k0 = (d0 > wd) | ((d0 == wd) & ((j + 0) > wi));
      bool k1 = (d1 > wd) | ((d1 == wd) & ((j + 1) > wi));
      bool k2 = (d2 > wd) | ((d2 == wd) & ((j + 2) > wi));
      bool k3 = (d3 > wd) | ((d3 == wd) & ((j + 3) > wi));
      bool k4 = (d4 > wd) | ((d4 == wd) & ((j + 4) > wi));
      bool k5 = (d5 > wd) | ((d5 == wd) & ((j + 5) > wi));
      bool k6 = (d6 > wd) | ((d6 == wd) & ((j + 6) > wi));
      bool k7 = (d7 > wd) | ((d7 == wd) & ((j + 7) > wi));
      d0 = k0 ? d0 : FLT_MAX;
      d1 = k1 ? d1 : FLT_MAX;
      d2 = k2 ? d2 : FLT_MAX;
      d3 = k3 ? d3 : FLT_MAX;
      d4 = k4 ? d4 : FLT_MAX;
      d5 = k5 ? d5 : FLT_MAX;
      d6 = k6 ? d6 : FLT_MAX;
      d7 = k7 ? d7 : FLT_MAX;
      TOURN8();
      bool lt = md < nd; nd = lt ? md : nd; ni = lt ? mi : ni;
    }
    WBK(0) WBK(1) WBK(2) WBK(3) WBK(4) WBK(5) WBK(6) WBK(7)
    WBK(8) WBK(9) WBK(10) WBK(11) WBK(12) WBK(13) WBK(14) WBK(15)
    WBK(16) WBK(17) WBK(18) WBK(19) WBK(20) WBK(21) WBK(22) WBK(23)
    WBK(24) WBK(25) WBK(26) WBK(27) WBK(28) WBK(29) WBK(30) WBK(31)
  }
}

__launch_bounds__(128, 4)
__global__ void k_knn(const float* __restrict__ x, uint2* __restrict__ PBDI,
                      double* __restrict__ ACC) {
  __shared__ f4 CH[NGROUP * GSTRIDE];   // 16896 B; 8 blocks/CU = 135 KB
  int bid = blockIdx.x;
  // fold ACC zeroing into the first kernel (saves the memset dispatch);
  // launch boundary orders this before k_tail1's atomics. Verified benign
  // in R7 (k_knn 110.0 with fold vs 108.7 without — noise band).
  if (bid == 0) {
    for (int t = threadIdx.x; t < NCOPY * 40; t += 128) ACC[t] = 0.0;
  }
  int pg = bid >> 3;                 // 128-point range [0,256)
  int s = bid & (SPLIT - 1);
  int p = pg * 128 + threadIdx.x;
  int b = p >> 13;                   // block-uniform (128-aligned range)
  int n = p & (N_ - 1);
  int bO = b * N_;
  int j0 = s * CHUNK;

  const float* xq = x + 3 * (size_t)p;
  float qa = xq[0], qb = xq[1], qc = xq[2];
  float qw = qa * qa + qb * qb + qc * qc;   // EXACT expression everywhere
  f32x2 qx2 = {qa, qa}, qy2 = {qb, qb}, qz2 = {qc, qc}, qw2 = {qw, qw};

  for (int u = threadIdx.x; u < CHUNK / 2; u += 128) {   // 512 pairs
    const float* xp = x + 3 * (size_t)(bO + j0 + 2 * u);
    float a0 = xp[0], b0 = xp[1], c0 = xp[2];
    float a1 = xp[3], b1 = xp[4], c1 = xp[5];
    int G = u >> 4, rr = u & 15;
    f4 lo = {a0, a1, b0, b1};
    f4 hi = {c0, c1, a0 * a0 + b0 * b0 + c0 * c0, a1 * a1 + b1 * b1 + c1 * c1};
    CH[G * GSTRIDE + 2 * rr] = lo;
    CH[G * GSTRIDE + 2 * rr + 1] = hi;
  }
  __syncthreads();

  int n0 = (pg * 128) & (N_ - 1);    // block-uniform
  int nl = n - j0;                   // local self index (valid only if HS)
  if (s == (n0 >> 10)) knn_chunk<true >(CH, qx2, qy2, qz2, qw2, nl, j0, s, p, PBDI);
  else                 knn_chunk<false>(CH, qx2, qy2, qz2, qw2, nl, j0, s, p, PBDI);
}

// ---------------- K2: merge + phi-sort + features + W1 -> H1 + stats1 ----------
// ROUND-6/8 FORM VERBATIM (verified tail). 512 blocks x 256 threads.
#define LVL(bdv, biv)                                                     \
  { bool lt = cd < (bdv); float td = (bdv); int ti = (biv);               \
    (bdv) = lt ? cd : (bdv); (biv) = lt ? ci : (biv);                     \
    cd = lt ? td : cd; ci = lt ? ti : ci; }
#define INS9ALL()                                                         \
  LVL(b0d, b0i) LVL(b1d, b1i) LVL(b2d, b2i) LVL(b3d, b3i) LVL(b4d, b4i)  \
  LVL(b5d, b5i) LVL(b6d, b6i) LVL(b7d, b7i) LVL(b8d, b8i)
#define TOP9_DECL()                                                       \
  float b0d = FLT_MAX, b1d = FLT_MAX, b2d = FLT_MAX, b3d = FLT_MAX,       \
        b4d = FLT_MAX, b5d = FLT_MAX, b6d = FLT_MAX, b7d = FLT_MAX,       \
        b8d = FLT_MAX;                                                    \
  int b0i = 0, b1i = 0, b2i = 0, b3i = 0, b4i = 0, b5i = 0, b6i = 0,      \
      b7i = 0, b8i = 0;

#define MKREL(T)                                                          \
  float rx##T, ry##T, rz##T, ph##T;                                       \
  { const float* mp = x + 3 * (size_t)(bO + b##T##i);                     \
    rx##T = mp[0] - qa; ry##T = mp[1] - qb; rz##T = mp[2] - qc;           \
    ph##T = atan2f(ry##T, rx##T); }

#define CE(A, Bv)                                                         \
  { bool lt = ph##Bv < ph##A; float t0;                                   \
    t0 = ph##A; ph##A = lt ? ph##Bv : t0; ph##Bv = lt ? t0 : ph##Bv;      \
    t0 = rx##A; rx##A = lt ? rx##Bv : t0; rx##Bv = lt ? t0 : rx##Bv;      \
    t0 = ry##A; ry##A = lt ? ry##Bv : t0; ry##Bv = lt ? t0 : ry##Bv;      \
    t0 = rz##A; rz##A = lt ? rz##Bv : t0; rz##Bv = lt ? t0 : rz##Bv; }

#define ST9(arr, v0, v1, v2, v3, v4, v5, v6, v7, v8)                      \
  arr[0 * 64 + pl] = v0; arr[1 * 64 + pl] = v1; arr[2 * 64 + pl] = v2;    \
  arr[3 * 64 + pl] = v3; arr[4 * 64 + pl] = v4; arr[5 * 64 + pl] = v5;    \
  arr[6 * 64 + pl] = v6; arr[7 * 64 + pl] = v7; arr[8 * 64 + pl] = v8;

__launch_bounds__(256, 4)
__global__ void k_tail1(const float* __restrict__ x, const uint2* __restrict__ PBDI,
                        const float* __restrict__ W1, const float* __restrict__ b1,
                        float* __restrict__ H1, double* __restrict__ ACC) {
  __shared__ float  LMD[64 * 37];        // [pl*37 + q*9 + r], odd stride
  __shared__ int    LMI[64 * 37];
  __shared__ float  LREL[3][9 * 64];     // [comp][t*64 + pl]
  __shared__ float  LSGN[64];
  __shared__ double sred[4][20];

  int q = threadIdx.x >> 6;              // wave id 0..3
  int pl = threadIdx.x & 63;
  int pbase = blockIdx.x * 64;
  int p = pbase + pl;

  // ---- sub-merge: wave q merges lists s in [2q, 2q+2) (18 coalesced entries)
  {
    TOP9_DECL();
#pragma clang loop unroll_count(2)
    for (int e = 0; e < 2 * K_; ++e) {
      uint2 v = PBDI[(size_t)(q * 2 * K_ + e) * NPTS + p];
      float cd = __uint_as_float(v.x);
      int ci = (int)v.y;
      INS9ALL();
    }
    int base = pl * 37 + q * 9;
    LMD[base + 0] = b0d; LMD[base + 1] = b1d; LMD[base + 2] = b2d;
    LMD[base + 3] = b3d; LMD[base + 4] = b4d; LMD[base + 5] = b5d;
    LMD[base + 6] = b6d; LMD[base + 7] = b7d; LMD[base + 8] = b8d;
    LMI[base + 0] = b0i; LMI[base + 1] = b1i; LMI[base + 2] = b2i;
    LMI[base + 3] = b3i; LMI[base + 4] = b4i; LMI[base + 5] = b5i;
    LMI[base + 6] = b6i; LMI[base + 7] = b7i; LMI[base + 8] = b8i;
  }
  __syncthreads();

  // ---- final merge + REL + phi-sort + sign (wave 0, one lane per point) ----
  if (q == 0) {
    int b = p >> 13;
    int bO = b * N_;
    const float* xq = x + 3 * (size_t)p;
    float qa = xq[0], qb = xq[1], qc = xq[2];

    TOP9_DECL();
#pragma clang loop unroll_count(3)
    for (int e = 0; e < 4 * K_; ++e) {   // ascending q (=s) then rank
      float cd = LMD[pl * 37 + e];
      int ci = LMI[pl * 37 + e];
      INS9ALL();
    }

    MKREL(0) MKREL(1) MKREL(2) MKREL(3) MKREL(4)
    MKREL(5) MKREL(6) MKREL(7) MKREL(8)

    // stable insertion-sort network ascending by phi (36 strict-< CEs)
    CE(0,1)
    CE(1,2) CE(0,1)
    CE(2,3) CE(1,2) CE(0,1)
    CE(3,4) CE(2,3) CE(1,2) CE(0,1)
    CE(4,5) CE(3,4) CE(2,3) CE(1,2) CE(0,1)
    CE(5,6) CE(4,5) CE(3,4) CE(2,3) CE(1,2) CE(0,1)
    CE(6,7) CE(5,6) CE(4,5) CE(3,4) CE(2,3) CE(1,2) CE(0,1)
    CE(7,8) CE(6,7) CE(5,6) CE(4,5) CE(3,4) CE(2,3) CE(1,2) CE(0,1)

    // sign from triangle 0's NORMALIZED nx (reference semantics)
    float nx0 = ry0 * rz1 - rz0 * ry1;
    float ny0 = rz0 * rx1 - rx0 * rz1;
    float nz0 = rx0 * ry1 - ry0 * rx1;
    float nrm0 = sqrtf(nx0 * nx0 + ny0 * ny0 + nz0 * nz0) + 1e-6f;
    LSGN[pl] = ((nx0 / nrm0) > 0.0f) ? 1.0f : -1.0f;

    ST9(LREL[0], rx0, rx1, rx2, rx3, rx4, rx5, rx6, rx7, rx8)
    ST9(LREL[1], ry0, ry1, ry2, ry3, ry4, ry5, ry6, ry7, ry8)
    ST9(LREL[2], rz0, rz1, rz2, rz3, rz4, rz5, rz6, rz7, rz8)
  }
  __syncthreads();

  // ---- rows: 576 rows / 256 threads; feat + W1 -> H1 + fp64 stats ----
  double sum[10], ss[10];
#pragma unroll
  for (int c = 0; c < 10; ++c) { sum[c] = 0.0; ss[c] = 0.0; }

#pragma clang loop unroll(disable)
  for (int rl = threadIdx.x; rl < 9 * 64; rl += 256) {
    int t = rl >> 6;
    int pp = rl & 63;
    int t2 = (t + 1 == K_) ? 0 : t + 1;
    float v1x = LREL[0][t * 64 + pp];
    float v1y = LREL[1][t * 64 + pp];
    float v1z = LREL[2][t * 64 + pp];
    float v2x = LREL[0][t2 * 64 + pp];
    float v2y = LREL[1][t2 * 64 + pp];
    float v2z = LREL[2][t2 * 64 + pp];
    float sgn = LSGN[pp];

    float cx = 0.5f * (v1x + v2x);
    float cy = 0.5f * (v1y + v2y);
    float cz = 0.5f * (v1z + v2z);
    float nx = v1y * v2z - v1z * v2y;
    float ny = v1z * v2x - v1x * v2z;
    float nz = v1x * v2y - v1y * v2x;
    float nrm = sqrtf(nx * nx + ny * ny + nz * nz) + 1e-6f;
    nx /= nrm; ny /= nrm; nz /= nrm;
    nx *= sgn; ny *= sgn; nz *= sgn;
    float pos = (nx * cx + ny * cy + nz * cz) / 1.7320508075688772f;

    float fv[7] = {cx, cy, cz, nx, ny, nz, pos};
#pragma unroll
    for (int c = 0; c < 10; ++c) {
      float h = b1[c];
#pragma unroll
      for (int rr = 0; rr < 7; ++rr) h = fmaf(fv[rr], W1[rr * 10 + c], h);
      H1[(size_t)c * NROWS + (size_t)t * NPTS + pbase + pp] = h;  // coalesced
      double hd = (double)h;
      sum[c] += hd; ss[c] += hd * hd;
    }
  }

  int lane = threadIdx.x & 63, wv = threadIdx.x >> 6;
#pragma unroll
  for (int c = 0; c < 10; ++c) {
    double a = sum[c];
#pragma unroll
    for (int off = 32; off > 0; off >>= 1) a += __shfl_down(a, off);
    if (lane == 0) sred[wv][c] = a;
    double qq = ss[c];
#pragma unroll
    for (int off = 32; off > 0; off >>= 1) qq += __shfl_down(qq, off);
    if (lane == 0) sred[wv][10 + c] = qq;
  }
  __syncthreads();
  if (threadIdx.x < 20) {
    // spread atomics over NCOPY accumulator copies (stride-40 layout:
    // copy c holds [0,20)=stats1, [20,40)=stats2)
    atomicAdd(&ACC[(blockIdx.x & (NCOPY - 1)) * 40 + threadIdx.x],
              sred[0][threadIdx.x] + sred[1][threadIdx.x] +
              sred[2][threadIdx.x] + sred[3][threadIdx.x]);
  }
}

// ---------------- K3: bn1 + relu + @W2+b2, PER-POINT; stats2 + EXT only --------
// ROUND-6/8 FORM VERBATIM (t-loop NOT unrolled). Each thread owns one point.
// Stores only the per-channel EXTREMUM over k (1.3 MB):
//   ext[c] = max_k h2 if g2[c] >= 0 else min_k h2.
// EXACTNESS: BN2+ReLU is an fp-MONOTONE map of h2 (IEEE rounding is monotone;
// rsig > 0; direction = sign(g2)), so max_k relu(bn2(h2_k)) ==
// relu(bn2(ext_k h2_k)) BIT-EXACTLY. k_out applies bn2+relu once to ext.
__launch_bounds__(64)
__global__ void k_mlp2(const float* __restrict__ H1, double* __restrict__ ACC,
                       const float* __restrict__ g1, const float* __restrict__ be1,
                       const float* __restrict__ W2, const float* __restrict__ b2,
                       const float* __restrict__ g2, float* __restrict__ EXT) {
  __shared__ float MR[20];
  __shared__ double sred[20];
  if (threadIdx.x < 20) {
    int c = threadIdx.x % 10;
    int half = threadIdx.x / 10;        // 0: mu, 1: rsigma
    double s0 = 0.0, s1 = 0.0;
#pragma unroll
    for (int cc = 0; cc < NCOPY; ++cc) {
      s0 += ACC[cc * 40 + c];
      s1 += ACC[cc * 40 + 10 + c];
    }
    double mu = s0 / (double)NROWS;
    double var = s1 / (double)NROWS - mu * mu;
    MR[threadIdx.x] = half ? (float)(1.0 / sqrt(var + 1e-5)) : (float)mu;
  }
  __syncthreads();

  int p = blockIdx.x * 64 + threadIdx.x;
  double sum[10], ss[10];
  float ext[10], sg[10];
#pragma unroll
  for (int c = 0; c < 10; ++c) {
    sum[c] = 0.0; ss[c] = 0.0;
    sg[c] = g2[c];
    ext[c] = (sg[c] >= 0.0f) ? -FLT_MAX : FLT_MAX;
  }

#pragma clang loop unroll(disable)
  for (int t = 0; t < K_; ++t) {
    float v[10];
#pragma unroll
    for (int c = 0; c < 10; ++c) {
      float h = H1[(size_t)c * NROWS + (size_t)t * NPTS + p];   // coalesced
      float z = g1[c] * (h - MR[c]) * MR[10 + c] + be1[c];
      v[c] = z > 0.0f ? z : 0.0f;
    }
#pragma unroll
    for (int c = 0; c < 10; ++c) {
      float h = b2[c];
#pragma unroll
      for (int u = 0; u < 10; ++u) h = fmaf(v[u], W2[u * 10 + c], h);
      sum[c] += (double)h;
      ss[c] += (double)h * (double)h;
      ext[c] = (sg[c] >= 0.0f) ? fmaxf(ext[c], h) : fminf(ext[c], h);
    }
  }

#pragma unroll
  for (int c = 0; c < 10; ++c)
    EXT[(size_t)c * NPTS + p] = ext[c];                          // coalesced

#pragma unroll
  for (int c = 0; c < 10; ++c) {
    double a = sum[c];
#pragma unroll
    for (int off = 32; off > 0; off >>= 1) a += __shfl_down(a, off);
    if (threadIdx.x == 0) sred[c] = a;
    double qq = ss[c];
#pragma unroll
    for (int off = 32; off > 0; off >>= 1) qq += __shfl_down(qq, off);
    if (threadIdx.x == 0) sred[10 + c] = qq;
  }
  __syncthreads();
  if (threadIdx.x < 20) {
    atomicAdd(&ACC[(blockIdx.x & (NCOPY - 1)) * 40 + 20 + threadIdx.x],
              sred[threadIdx.x]);
  }
}

// ---------------- K4: bn2(from ACC copies) + relu on the EXT value -> out ------
__launch_bounds__(64)
__global__ void k_out(const float* __restrict__ EXT, const double* __restrict__ ACC,
                      const float* __restrict__ g2, const float* __restrict__ be2,
                      float* __restrict__ out) {
  __shared__ float MR[20];
  if (threadIdx.x < 20) {
    int c = threadIdx.x % 10;
    int half = threadIdx.x / 10;        // 0: mu, 1: rsigma
    double s0 = 0.0, s1 = 0.0;
#pragma unroll
    for (int cc = 0; cc < NCOPY; ++cc) {
      s0 += ACC[cc * 40 + 20 + c];
      s1 += ACC[cc * 40 + 30 + c];
    }
    double mu = s0 / (double)NROWS;
    double var = s1 / (double)NROWS - mu * mu;
    MR[threadIdx.x] = half ? (float)(1.0 / sqrt(var + 1e-5)) : (float)mu;
  }
  __syncthreads();

  int p = blockIdx.x * 64 + threadIdx.x;
#pragma unroll
  for (int c = 0; c < 10; ++c) {
    float h = EXT[(size_t)c * NPTS + p];                         // coalesced
    float z = g2[c] * (h - MR[c]) * MR[10 + c] + be2[c];
    z = z > 0.0f ? z : 0.0f;
    out[(size_t)p * 10 + c] = z;
  }
}

extern "C" void kernel_launch(void* const* d_in, const int* in_sizes, int n_in,
                              void* d_out, int out_size, void* d_ws, size_t ws_size,
                              hipStream_t stream) {
  (void)in_sizes; (void)n_in; (void)out_size; (void)ws_size;
  const float* x  = (const float*)d_in[0];
  const float* W1 = (const float*)d_in[1];
  const float* b1 = (const float*)d_in[2];
  const float* g1 = (const float*)d_in[3];
  const float* be1= (const float*)d_in[4];
  const float* W2 = (const float*)d_in[5];
  const float* b2 = (const float*)d_in[6];
  const float* g2 = (const float*)d_in[7];
  const float* be2= (const float*)d_in[8];
  float* out = (float*)d_out;

  char* base = (char*)d_ws;
  uint2*  PBDI = (uint2*)base;                          // 72 slices, 18.9 MB
  float*  H1 = (float*)(base + (size_t)SPLIT * K_ * NPTS * 8);  // 11.8 MB
  double* ACC = (double*)(H1 + (size_t)10 * NROWS);     // NCOPY*40 doubles
  // EXT aliases PBDI (dead after k_tail1): 10*NPTS*4 = 1.3 of 18.9 MB
  float*  EXT = (float*)PBDI;

  k_knn<<<(NPTS / 128) * SPLIT, 128, 0, stream>>>(x, PBDI, ACC);
  k_tail1<<<NPTS / 64, 256, 0, stream>>>(x, PBDI, W1, b1, H1, ACC);
  k_mlp2<<<NPTS / 64, 64, 0, stream>>>(H1, ACC, g1, be1, W2, b2, g2, EXT);
  k_out<<<NPTS / 64, 64, 0, stream>>>(EXT, ACC, g2, be2, out);
}